// Round 10
// baseline (297.858 us; speedup 1.0000x reference)
//
#include <hip/hip_runtime.h>
#include <math.h>

// NoisyTopKRouter, round 10: force B into flight (explicit reg double-buffer + fences).
//   r9 ablation: B L1-hot clone ran ~60us vs 225us primary -> B-fetch latency is THE binder
//   (VGPR=60 showed compiler sinks B loads JIT). Fix: named cur/next B reg sets loaded a
//   full step ahead, sched_barrier(0) after each load block so they can't sink into MFMAs.
//   Geometry: 512 thr = 8 waves (2 kh x 4 nq), BM=32, grid 512, 4 waves/SIMD, no main-loop
//   barriers; 2-phase LDS reduce + proven epilogue. Diag kernel removed.
// Outputs (flat f32): gate_weights [N][64], top2 idx as float [N][2], logits [N][64].

typedef float   f32x4   __attribute__((ext_vector_type(4)));
typedef __bf16  bf16x8  __attribute__((ext_vector_type(8)));
typedef unsigned short ushort8 __attribute__((ext_vector_type(8)));

#define EE 64     // experts
#define E2 128    // gate+noise logit columns
#define BM 32     // tokens per block

__device__ __forceinline__ unsigned short bf16_rne(float f) {
    unsigned int u = __float_as_uint(f);
    u += 0x7fffu + ((u >> 16) & 1u);
    return (unsigned short)(u >> 16);
}
__device__ __forceinline__ float bf16_f32(unsigned short h) {
    return __uint_as_float(((unsigned int)h) << 16);
}
__device__ __forceinline__ void split3(float a, unsigned short& h1,
                                       unsigned short& h2, unsigned short& h3) {
    h1 = bf16_rne(a);
    float r  = a - bf16_f32(h1);     // exact
    h2 = bf16_rne(r);
    float r2 = r - bf16_f32(h2);     // exact
    h3 = bf16_rne(r2);
}

// ---- pre-kernel: pack W (gate cols 0..63, noise cols 64..127) into B-frag order.
// Fragment (16x16x32 bf16, verified): lane l holds col=l&15, k=(l>>4)*8+j.
// Packed ushort addr: ((ks*8 + nt)*3 + term)*512 + lane*8 + j   (ks = k/32)
__global__ __launch_bounds__(256) void pack_b(
    const float* __restrict__ wg, const float* __restrict__ wn,
    unsigned short* __restrict__ bp, int Hdim)
{
    int pair = blockIdx.x * 4 + (threadIdx.x >> 6);   // (ks, nt)
    int l    = threadIdx.x & 63;
    int ks   = pair >> 3;
    int nt   = pair & 7;
    int col  = nt * 16 + (l & 15);
    int k    = ks * 32 + ((l >> 4) * 8);
    const float* wrow = (col < EE) ? (wg + (size_t)col * Hdim)
                                   : (wn + (size_t)(col - EE) * Hdim);
    float4 v0 = *reinterpret_cast<const float4*>(wrow + k);
    float4 v1 = *reinterpret_cast<const float4*>(wrow + k + 4);
    float vals[8] = {v0.x, v0.y, v0.z, v0.w, v1.x, v1.y, v1.z, v1.w};
    ushort8 t1, t2, t3;
    #pragma unroll
    for (int j = 0; j < 8; ++j) {
        unsigned short a, b, c;
        split3(vals[j], a, b, c);
        t1[j] = a; t2[j] = b; t3[j] = c;
    }
    size_t base = ((size_t)(ks * 8 + nt) * 3) * 512 + (size_t)l * 8;
    *reinterpret_cast<ushort8*>(bp + base        ) = t1;
    *reinterpret_cast<ushort8*>(bp + base + 512  ) = t2;
    *reinterpret_cast<ushort8*>(bp + base + 1024 ) = t3;
}

#define MFMA(a, b, c) __builtin_amdgcn_mfma_f32_16x16x32_bf16((a), (b), (c), 0, 0, 0)
#define SB0() __builtin_amdgcn_sched_barrier(0)

__global__ __launch_bounds__(512, 4) void router_mfma(
    const float* __restrict__ hs,
    const float* __restrict__ noise,
    const unsigned short* __restrict__ bp,
    float* __restrict__ out_gate,
    float* __restrict__ out_idx,
    float* __restrict__ out_logits,
    int Ntok, int Hdim)
{
    __shared__ float Lred[BM][E2 + 5];   // stride 133 -> conflict-free scalar reads

    const int tid  = threadIdx.x;
    const int lane = tid & 63;
    const int w    = tid >> 6;           // wave 0..7
    const int kh   = w & 1;              // K-half 0..1
    const int nq   = w >> 1;             // N-quarter 0..3 (cols nq*32 .. nq*32+31)
    const int m0   = blockIdx.x * BM;

    const int khalf = Hdim >> 1;         // 2048
    const int steps = khalf >> 5;        // 64 (even)
    const int ks0   = kh * steps;

    f32x4 acc[2][2];
    #pragma unroll
    for (int mt = 0; mt < 2; ++mt)
        #pragma unroll
        for (int n = 0; n < 2; ++n) acc[mt][n] = f32x4{0.f, 0.f, 0.f, 0.f};

    // A sources: lane l covers row (l&15) of m-tile mt, k-octet (l>>4)*8, this K-half.
    const float* pa0 = hs + (size_t)(m0 + (lane & 15)) * Hdim
                          + (size_t)kh * khalf + ((lane >> 4) * 8);
    const float* pa1 = pa0 + (size_t)16 * Hdim;

    // B base: this wave's 6 fragment slots (nt = nq*2+{0,1}, 3 terms each).
    const unsigned short* pbw = bp + (size_t)(nq * 6) * 512 + (size_t)lane * 8;

    #define LOADA(d00, d01, d10, d11)                                         \
        do {                                                                  \
            d00 = *reinterpret_cast<const float4*>(pa0);                      \
            d01 = *reinterpret_cast<const float4*>(pa0 + 4);                  \
            d10 = *reinterpret_cast<const float4*>(pa1);                      \
            d11 = *reinterpret_cast<const float4*>(pa1 + 4);                  \
            pa0 += 32; pa1 += 32;                                             \
        } while (0)

    // Load 6 B fragments for k-step ks into a named array (compile-time indices).
    #define LOADB(dB, s)                                                      \
        do {                                                                  \
            const unsigned short* pb =                                        \
                pbw + (size_t)(ks0 + (s)) * 12288;                            \
            _Pragma("unroll")                                                 \
            for (int fi = 0; fi < 6; ++fi)                                    \
                dB[fi] = *reinterpret_cast<const ushort8*>(pb + fi * 512);    \
        } while (0)

    #define SPLIT(s0, s1, A1, A2, A3)                                         \
        do {                                                                  \
            float vals[8] = {s0.x, s0.y, s0.z, s0.w, s1.x, s1.y, s1.z, s1.w}; \
            _Pragma("unroll")                                                 \
            for (int j = 0; j < 8; ++j) {                                     \
                float a  = vals[j];                                           \
                __bf16 h1 = (__bf16)a;                                        \
                float r  = a - (float)h1;                                     \
                __bf16 h2 = (__bf16)r;                                        \
                float r2 = r - (float)h2;                                     \
                __bf16 h3 = (__bf16)r2;                                       \
                A1[j] = h1; A2[j] = h2; A3[j] = h3;                           \
            }                                                                 \
        } while (0)

    #define COMPUTE(a00, a01, a10, a11, B)                                    \
        do {                                                                  \
            bf16x8 A1a, A2a, A3a, A1b, A2b, A3b;                              \
            SPLIT(a00, a01, A1a, A2a, A3a);                                   \
            SPLIT(a10, a11, A1b, A2b, A3b);                                   \
            _Pragma("unroll")                                                 \
            for (int n = 0; n < 2; ++n) {                                     \
                bf16x8 b1 = __builtin_bit_cast(bf16x8, B[n * 3 + 0]);         \
                bf16x8 b2 = __builtin_bit_cast(bf16x8, B[n * 3 + 1]);         \
                bf16x8 b3 = __builtin_bit_cast(bf16x8, B[n * 3 + 2]);         \
                __builtin_amdgcn_s_setprio(1);                                \
                acc[0][n] = MFMA(A1a, b1, acc[0][n]);                         \
                acc[0][n] = MFMA(A1a, b2, acc[0][n]);                         \
                acc[0][n] = MFMA(A2a, b1, acc[0][n]);                         \
                acc[0][n] = MFMA(A2a, b2, acc[0][n]);                         \
                acc[0][n] = MFMA(A1a, b3, acc[0][n]);                         \
                acc[0][n] = MFMA(A3a, b1, acc[0][n]);                         \
                acc[1][n] = MFMA(A1b, b1, acc[1][n]);                         \
                acc[1][n] = MFMA(A1b, b2, acc[1][n]);                         \
                acc[1][n] = MFMA(A2b, b1, acc[1][n]);                         \
                acc[1][n] = MFMA(A2b, b2, acc[1][n]);                         \
                acc[1][n] = MFMA(A1b, b3, acc[1][n]);                         \
                acc[1][n] = MFMA(A3b, b1, acc[1][n]);                         \
                __builtin_amdgcn_s_setprio(0);                                \
            }                                                                 \
        } while (0)

    // ---- barrier-free main loop; B AND A double-buffered in named registers.
    //      Loads for step s+1 are issued BEFORE COMPUTE(s); sched_barrier(0)
    //      pins them above the MFMA region so the scheduler cannot sink them.
    float4 cA00, cA01, cA10, cA11, nA00, nA01, nA10, nA11;
    ushort8 cB[6], nB[6];

    LOADB(cB, 0);
    LOADA(cA00, cA01, cA10, cA11);
    SB0();

    for (int s = 0; s < steps; s += 2) {
        LOADB(nB, s + 1);                              // prefetch step s+1
        LOADA(nA00, nA01, nA10, nA11);
        SB0();
        COMPUTE(cA00, cA01, cA10, cA11, cB);           // step s
        if (s + 2 < steps) {
            LOADB(cB, s + 2);                          // prefetch step s+2
            LOADA(cA00, cA01, cA10, cA11);
        }
        SB0();
        COMPUTE(nA00, nA01, nA10, nA11, nB);           // step s+1
    }

    // ---- 2-phase cross-half reduction (nq waves write disjoint cols) ----
    // C/D frag (verified): reg r -> row=(lane>>4)*4+r, col=lane&15.
    if (kh == 0) {
        #pragma unroll
        for (int mt = 0; mt < 2; ++mt)
            #pragma unroll
            for (int n = 0; n < 2; ++n)
                #pragma unroll
                for (int r = 0; r < 4; ++r)
                    Lred[mt * 16 + (lane >> 4) * 4 + r]
                        [(nq * 2 + n) * 16 + (lane & 15)] = acc[mt][n][r];
    }
    __syncthreads();
    if (kh == 1) {
        #pragma unroll
        for (int mt = 0; mt < 2; ++mt)
            #pragma unroll
            for (int n = 0; n < 2; ++n)
                #pragma unroll
                for (int r = 0; r < 4; ++r)
                    Lred[mt * 16 + (lane >> 4) * 4 + r]
                        [(nq * 2 + n) * 16 + (lane & 15)] += acc[mt][n][r];
    }
    __syncthreads();

    // ---- per-token epilogue (proven path): one thread per token ----
    if (tid < BM) {
        const int t   = tid;
        const int tok = m0 + t;
        const float* nrow = noise + (size_t)tok * EE;
        float* lrow = out_logits + (size_t)tok * EE;

        float m = -3.4e38f;
        for (int e = 0; e < EE; ++e) {
            float gv = Lred[t][e];
            float nv = Lred[t][EE + e];
            float sp = fmaxf(nv, 0.f) + log1pf(expf(-fabsf(nv)));  // stable softplus
            float l  = fmaf(nrow[e], sp, gv);                      // NOISE_STD = 1
            lrow[e]  = l;
            Lred[t][e] = l;
            m = fmaxf(m, l);
        }

        float Z = 0.f;
        float p1 = -1.f, p2 = -1.f;
        int   i1 = 0,    i2 = 0;
        for (int e = 0; e < EE; ++e) {
            float p = expf(Lred[t][e] - m);
            Z += p;
            if (p > p1)      { p2 = p1; i2 = i1; p1 = p; i1 = e; }  // ties -> lower idx
            else if (p > p2) { p2 = p;  i2 = e; }
        }
        float q1 = p1 / Z, q2 = p2 / Z;
        float denom = q1 + q2 + 1e-9f;
        float w1 = q1 / denom, w2 = q2 / denom;

        out_idx[(size_t)tok * 2 + 0] = (float)i1;
        out_idx[(size_t)tok * 2 + 1] = (float)i2;

        float* grow = out_gate + (size_t)tok * EE;
        for (int e = 0; e < EE; ++e)
            grow[e] = (e == i1) ? w1 : ((e == i2) ? w2 : 0.f);
    }
}

extern "C" void kernel_launch(void* const* d_in, const int* in_sizes, int n_in,
                              void* d_out, int out_size, void* d_ws, size_t ws_size,
                              hipStream_t stream) {
    const float* hs    = (const float*)d_in[0];
    const float* noise = (const float*)d_in[1];
    const float* wg    = (const float*)d_in[2];
    const float* wn    = (const float*)d_in[3];

    const int Ntok = in_sizes[1] / EE;    // noise is [N][64]
    const int Hdim = in_sizes[2] / EE;    // w_gate is [64][H]

    float* out_gate   = (float*)d_out;
    float* out_idx    = out_gate + (size_t)Ntok * EE;
    float* out_logits = out_idx  + (size_t)Ntok * 2;

    unsigned short* bp = (unsigned short*)d_ws;   // needs (H/32)*8*3*512*2 = 3 MB

    // pack W into MFMA B-fragment layout (3 bf16 terms)
    int pairs = (Hdim / 32) * 8;
    hipLaunchKernelGGL(pack_b, dim3(pairs / 4), dim3(256), 0, stream, wg, wn, bp, Hdim);

    hipLaunchKernelGGL(router_mfma, dim3(Ntok / BM), dim3(512), 0, stream,
                       hs, noise, bp, out_gate, out_idx, out_logits, Ntok, Hdim);
}